// Round 4
// baseline (907.666 us; speedup 1.0000x reference)
//
#include <hip/hip_runtime.h>

#define L_ 8
#define B_ 16
#define D_ 1024
#define JT 32              // output-column tile per block
#define IG 8               // i-groups per block
#define ILEN (D_ / IG)     // 128 reduction rows per i-group
#define NBLK (B_ * (D_ / JT))   // 512 blocks

// Persistent per-sample-chain kernel. Block (b, jt) computes
// out[b, jt*32 .. jt*32+32) for every layer; the 32 blocks of sample b
// synchronize through a device-scope atomic counter per (layer, sample).
__global__ __launch_bounds__(256) void discocirc_chain(
    const float* __restrict__ x,     // [B][D]
    const float* __restrict__ W,     // [L][B][D][D]
    const float* __restrict__ Bs,    // [L][B][D]
    const int*   __restrict__ M,     // [L][B][D]
    float* __restrict__ out,         // [B][D]
    float* hbuf,                     // (L-1) * B*D floats
    int*   bar)                      // (L-1) * B ints, zeroed before launch
{
    // blockIdx = jt*16 + b  ->  all 32 blocks of sample b share blockIdx%16,
    // hence (with round-robin XCD mapping) the same XCD.
    const int b   = blockIdx.x & (B_ - 1);
    const int jt  = blockIdx.x >> 4;
    const int tid = threadIdx.x;
    const int jl  = tid & 31;        // lane within j-tile
    const int ig  = tid >> 5;        // i-group 0..7

    __shared__ float hs[D_];
    __shared__ float red[IG][JT];

    const size_t wstride = (size_t)D_ * D_;
    const float* Wb = W + (size_t)b * wstride
                    + (size_t)(ig * ILEN) * D_ + jt * JT + jl;

    for (int l = 0; l < L_; ++l) {
        const float* hin = (l == 0) ? x : hbuf + (size_t)(l - 1) * B_ * D_;
        ((float4*)hs)[tid] = ((const float4*)(hin + (size_t)b * D_))[tid];
        __syncthreads();

        const float* Wp = Wb + (size_t)l * B_ * wstride;
        const float* hp = hs + ig * ILEN;

        float acc = 0.f;
#pragma unroll 16
        for (int i = 0; i < ILEN; ++i) {
            acc += hp[i] * Wp[(size_t)i * D_];
        }

        red[ig][jl] = acc;
        __syncthreads();

        if (tid < JT) {
            const int t = b * D_ + jt * JT + tid;
            float s = Bs[(size_t)l * B_ * D_ + t];
#pragma unroll
            for (int g = 0; g < IG; ++g) s += red[g][tid];
            if (M[(size_t)l * B_ * D_ + t]) s = fmaxf(s, 0.f);
            float* hout = (l == L_ - 1) ? out : hbuf + (size_t)l * B_ * D_;
            hout[t] = s;
        }

        if (l + 1 < L_) {
            __threadfence();                 // release: h writes -> agent scope
            __syncthreads();                 // writers' fences complete
            if (tid == 0) {
                int* c = &bar[l * B_ + b];
                atomicAdd(c, 1);             // device-scope by default
                while (__hip_atomic_load(c, __ATOMIC_RELAXED,
                                         __HIP_MEMORY_SCOPE_AGENT) < (D_ / JT)) { }
                __threadfence();             // acquire in observing thread
            }
            __syncthreads();
            __threadfence();                 // invalidate stale L1/L2 lines
        }
    }
}

extern "C" void kernel_launch(void* const* d_in, const int* in_sizes, int n_in,
                              void* d_out, int out_size, void* d_ws, size_t ws_size,
                              hipStream_t stream) {
    const float* x  = (const float*)d_in[0];
    const float* W  = (const float*)d_in[1];
    const float* Bs = (const float*)d_in[2];
    const int*   M  = (const int*)d_in[3];
    float* out = (float*)d_out;

    int*   bar  = (int*)d_ws;                        // (L-1)*B = 112 ints
    float* hbuf = (float*)((char*)d_ws + 512);       // (L-1)*B*D floats

    hipMemsetAsync(bar, 0, (L_ - 1) * B_ * sizeof(int), stream);
    discocirc_chain<<<NBLK, 256, 0, stream>>>(x, W, Bs, M, out, hbuf, bar);
}

// Round 5
// 126.880 us; speedup vs baseline: 7.1537x; 7.1537x over previous
//
#include <hip/hip_runtime.h>

#define L_ 8
#define B_ 16
#define D_ 1024
#define JT 32                  // output columns per block
#define TPR 8                  // threads per row (each thread = float4 -> 32 cols)
#define IG 32                  // i-groups per block (256 / TPR)
#define ILEN (D_ / IG)         // 32 reduction rows per group
#define HPAD(i) ((i) + ((i) >> 5))   // +1 float pad per 32 -> conflict-free ig-stride reads

// One block computes out[b, jt*32 .. jt*32+32) with the full i-reduction.
// Grid: B_*32 = 512 blocks, 256 threads. W loads are float4 (16B/lane).
__global__ __launch_bounds__(256) void layer_full(
    const float* __restrict__ h,     // [B][D]
    const float* __restrict__ W,     // layer base [B][D][D]
    const float* __restrict__ bias,  // layer base [B][D]
    const int*   __restrict__ mask,  // layer base [B][D]
    float* __restrict__ hout)        // [B][D]
{
    const int b   = blockIdx.x >> 5;
    const int jt  = blockIdx.x & 31;
    const int tid = threadIdx.x;
    const int q   = tid & (TPR - 1);   // column-quad within the 32-col tile
    const int ig  = tid >> 3;          // i-group 0..31

    __shared__ float hs[D_ + (D_ >> 5)];        // padded h stage (4.2 KB)
    __shared__ float4 red4[IG][TPR];            // 4 KB partials
    __shared__ float red2[8][JT];               // 1 KB stage-2

    {   // stage h[b,:] padded: each thread 1 float4 -> 4 scalars
        const float4 v = ((const float4*)(h + (size_t)b * D_))[tid];
        const int i0 = tid * 4;
        hs[HPAD(i0 + 0)] = v.x;  hs[HPAD(i0 + 1)] = v.y;
        hs[HPAD(i0 + 2)] = v.z;  hs[HPAD(i0 + 3)] = v.w;
    }
    __syncthreads();

    // Thread reads W[b][row][jt*32 + q*4 .. +4) as float4; 8 lanes x 16B = one
    // contiguous 128B segment per row.
    const float4* __restrict__ W4 =
        (const float4*)(W + (size_t)b * D_ * D_)
        + (size_t)(ig * ILEN) * (D_ / 4) + jt * (JT / 4) + q;
    const int hbase = ig * ILEN;

    float4 acc = {0.f, 0.f, 0.f, 0.f};
#pragma unroll 16
    for (int i = 0; i < ILEN; ++i) {
        const float hv = hs[HPAD(hbase + i)];
        const float4 w = W4[(size_t)i * (D_ / 4)];
        acc.x += hv * w.x;  acc.y += hv * w.y;
        acc.z += hv * w.z;  acc.w += hv * w.w;
    }
    red4[ig][q] = acc;
    __syncthreads();

    {   // stage 1: each thread sums 4 i-groups for one column
        const float* red = (const float*)red4;          // [IG][JT] floats
        const int c = tid & 31, g0 = (tid >> 5) << 2;
        float s = 0.f;
#pragma unroll
        for (int g = 0; g < 4; ++g) s += red[(g0 + g) * JT + c];
        red2[tid >> 5][c] = s;
    }
    __syncthreads();

    if (tid < JT) {   // stage 2 + bias + masked ReLU + store
        const int t = b * D_ + jt * JT + tid;
        float s = bias[t];
#pragma unroll
        for (int g = 0; g < 8; ++g) s += red2[g][tid];
        if (mask[t]) s = fmaxf(s, 0.f);
        hout[t] = s;
    }
}

extern "C" void kernel_launch(void* const* d_in, const int* in_sizes, int n_in,
                              void* d_out, int out_size, void* d_ws, size_t ws_size,
                              hipStream_t stream) {
    const float* x  = (const float*)d_in[0];
    const float* W  = (const float*)d_in[1];
    const float* Bs = (const float*)d_in[2];
    const int*   M  = (const int*)d_in[3];

    float* hA = (float*)d_ws;
    float* hB = hA + (size_t)B_ * D_;

    const float* hin = x;
    for (int l = 0; l < L_; ++l) {
        float* hout = (l == L_ - 1) ? (float*)d_out : ((l & 1) ? hB : hA);
        layer_full<<<B_ * 32, 256, 0, stream>>>(
            hin,
            W  + (size_t)l * B_ * D_ * D_,
            Bs + (size_t)l * B_ * D_,
            M  + (size_t)l * B_ * D_,
            hout);
        hin = hout;
    }
}

// Round 6
// 110.780 us; speedup vs baseline: 8.1934x; 1.1453x over previous
//
#include <hip/hip_runtime.h>

#define L_ 8
#define B_ 16
#define D_ 1024
#define JT 32              // output-column tile per block
#define IG 8               // i-groups per block (tid >> 5)
#define ILEN (D_ / IG)     // 128 reduction rows per i-group

// One block computes out[b, jt*JT : (jt+1)*JT] with the FULL i-reduction.
// Grid: B_ * (D_/JT) = 512 blocks, 256 threads.
__global__ __launch_bounds__(256) void layer_full(
    const float* __restrict__ h,     // [B][D] input activations
    const float* __restrict__ W,     // layer base [B][D][D]
    const float* __restrict__ bias,  // layer base [B][D]
    const int*   __restrict__ mask,  // layer base [B][D]
    float* __restrict__ hout)        // [B][D]
{
    const int blk = blockIdx.x;
    const int b   = blk / (D_ / JT);
    const int jt  = blk % (D_ / JT);
    const int tid = threadIdx.x;
    const int jl  = tid & 31;        // lane within j-tile
    const int ig  = tid >> 5;        // i-group 0..7

    __shared__ float hs[D_];
    {   // cooperative float4 load of h[b,:] (256 threads x 16B = 4KB)
        const float4* h4 = (const float4*)(h + (size_t)b * D_);
        ((float4*)hs)[tid] = h4[tid];
    }
    __syncthreads();

    // Thread reads W[b][i][jt*JT + jl] for i in its group; 32 lanes -> one
    // contiguous 128B segment per row. W is streamed once -> nontemporal.
    const float* __restrict__ Wp =
        W + (size_t)b * D_ * D_ + (size_t)(ig * ILEN) * D_ + jt * JT + jl;
    const float* __restrict__ hp = hs + ig * ILEN;

    float acc = 0.f;
#pragma unroll 32
    for (int i = 0; i < ILEN; ++i) {
        acc += hp[i] * __builtin_nontemporal_load(&Wp[(size_t)i * D_]);
    }

    // Hoist the tiny epilogue loads so they overlap the LDS reduce.
    float bsv = 0.f;
    int   mv  = 0;
    const int t = b * D_ + jt * JT + (tid & 31);
    if (tid < JT) { bsv = bias[t]; mv = mask[t]; }

    __shared__ float red[IG][JT];
    red[ig][jl] = acc;
    __syncthreads();

    if (tid < JT) {
        float s = bsv;
#pragma unroll
        for (int g = 0; g < IG; ++g) s += red[g][tid];
        if (mv) s = fmaxf(s, 0.f);
        hout[t] = s;
    }
}

extern "C" void kernel_launch(void* const* d_in, const int* in_sizes, int n_in,
                              void* d_out, int out_size, void* d_ws, size_t ws_size,
                              hipStream_t stream) {
    const float* x  = (const float*)d_in[0];
    const float* W  = (const float*)d_in[1];
    const float* Bs = (const float*)d_in[2];
    const int*   M  = (const int*)d_in[3];

    float* hA = (float*)d_ws;
    float* hB = hA + (size_t)B_ * D_;

    const float* hin = x;
    for (int l = 0; l < L_; ++l) {
        float* hout = (l == L_ - 1) ? (float*)d_out : ((l & 1) ? hB : hA);
        layer_full<<<B_ * (D_ / JT), 256, 0, stream>>>(
            hin,
            W  + (size_t)l * B_ * D_ * D_,
            Bs + (size_t)l * B_ * D_,
            M  + (size_t)l * B_ * D_,
            hout);
        hin = hout;
    }
}

// Round 7
// 109.250 us; speedup vs baseline: 8.3082x; 1.0140x over previous
//
#include <hip/hip_runtime.h>

#define L_ 8
#define B_ 16
#define D_ 1024
#define JT 32              // output-column tile per block
#define IG 8               // i-groups per block (tid >> 5)
#define ILEN (D_ / IG)     // 128 reduction rows per i-group
#define PF 32              // W rows prefetched before the h stage

// One block computes out[b, jt*JT : (jt+1)*JT] with the FULL i-reduction.
// Grid: B_ * (D_/JT) = 512 blocks, 256 threads.
__global__ __launch_bounds__(256) void layer_full(
    const float* __restrict__ h,     // [B][D] input activations
    const float* __restrict__ W,     // layer base [B][D][D]
    const float* __restrict__ bias,  // layer base [B][D]
    const int*   __restrict__ mask,  // layer base [B][D]
    float* __restrict__ hout)        // [B][D]
{
    const int blk = blockIdx.x;
    const int b   = blk / (D_ / JT);
    const int jt  = blk % (D_ / JT);
    const int tid = threadIdx.x;
    const int jl  = tid & 31;        // lane within j-tile
    const int ig  = tid >> 5;        // i-group 0..7

    // 1) Issue the dependent h load FIRST (it heads the vmcnt queue).
    const float4 hv4 = ((const float4*)(h + (size_t)b * D_))[tid];

    // 2) Then issue a 32-row W prefetch. Because h was issued first, the
    //    ds_write below only needs vmcnt(PF) — these stay in flight through
    //    the h stage and the barrier.
    const float* __restrict__ Wp =
        W + (size_t)b * D_ * D_ + (size_t)(ig * ILEN) * D_ + jt * JT + jl;
    float pf[PF];
#pragma unroll
    for (int p = 0; p < PF; ++p)
        pf[p] = __builtin_nontemporal_load(&Wp[(size_t)p * D_]);

    __shared__ float hs[D_];
    ((float4*)hs)[tid] = hv4;

    // Hoist the tiny epilogue loads (issued behind the prefetch, used last).
    float bsv = 0.f;
    int   mv  = 0;
    const int t = b * D_ + jt * JT + (tid & 31);
    if (tid < JT) { bsv = bias[t]; mv = mask[t]; }

    __syncthreads();

    const float* __restrict__ hp = hs + ig * ILEN;

    float acc = 0.f;
#pragma unroll
    for (int p = 0; p < PF; ++p) acc += hp[p] * pf[p];
#pragma unroll 32
    for (int i = PF; i < ILEN; ++i)
        acc += hp[i] * __builtin_nontemporal_load(&Wp[(size_t)i * D_]);

    __shared__ float red[IG][JT];
    red[ig][jl] = acc;
    __syncthreads();

    if (tid < JT) {
        float s = bsv;
#pragma unroll
        for (int g = 0; g < IG; ++g) s += red[g][tid];
        if (mv) s = fmaxf(s, 0.f);
        hout[t] = s;
    }
}

extern "C" void kernel_launch(void* const* d_in, const int* in_sizes, int n_in,
                              void* d_out, int out_size, void* d_ws, size_t ws_size,
                              hipStream_t stream) {
    const float* x  = (const float*)d_in[0];
    const float* W  = (const float*)d_in[1];
    const float* Bs = (const float*)d_in[2];
    const int*   M  = (const int*)d_in[3];

    float* hA = (float*)d_ws;
    float* hB = hA + (size_t)B_ * D_;

    const float* hin = x;
    for (int l = 0; l < L_; ++l) {
        float* hout = (l == L_ - 1) ? (float*)d_out : ((l & 1) ? hB : hA);
        layer_full<<<B_ * (D_ / JT), 256, 0, stream>>>(
            hin,
            W  + (size_t)l * B_ * D_ * D_,
            Bs + (size_t)l * B_ * D_,
            M  + (size_t)l * B_ * D_,
            hout);
        hin = hout;
    }
}